// Round 3
// baseline (279.342 us; speedup 1.0000x reference)
//
#include <hip/hip_runtime.h>
#include <math.h>

#define Ss 1024
#define Dd 1024
#define Hh 16
#define Kk 64

typedef __bf16 bf16x8 __attribute__((ext_vector_type(8)));
typedef __bf16 bf16x4 __attribute__((ext_vector_type(4)));
typedef float  f32x4  __attribute__((ext_vector_type(4)));

#define MFMA16(a, b, c) __builtin_amdgcn_mfma_f32_16x16x32_bf16(a, b, c, 0, 0, 0)

// ws element offsets (bf16 units)
#define XB_E   8388608u
#define WT_E   3145728u
#define WOT_E  1048576u
#define QKV_E  8388608u

// v_exp_f32 is natively 2^x; log2(e) is folded into the Q scale in gemm.
__device__ __forceinline__ float exp2_hw(float x) {
    float r; asm("v_exp_f32 %0, %1" : "=v"(r) : "v"(x)); return r;
}

// global -> LDS DMA, 16B per lane. LDS dest: wave-uniform base + lane*16.
typedef __attribute__((address_space(1))) const void gas_void;
typedef __attribute__((address_space(3))) void las_void;
__device__ __forceinline__ void gll16(const __bf16* g, char* l) {
    __builtin_amdgcn_global_load_lds((gas_void*)g, (las_void*)l, 16, 0, 0);
}

// ---------------------------------------------------------------------------
// prep: z<4 -> transpose+cast weight matrix z; z==4 -> cast x to bf16
// ---------------------------------------------------------------------------
__global__ __launch_bounds__(256) void prep(
    const float* __restrict__ x,
    const float* __restrict__ Wq, const float* __restrict__ Wk,
    const float* __restrict__ Wv, const float* __restrict__ Wo,
    __bf16* __restrict__ xb, __bf16* __restrict__ WT, __bf16* __restrict__ WoT)
{
    __shared__ float tile[64][65];
    const int z = blockIdx.z;
    const int t = threadIdx.x;

    if (z == 4) {   // x cast: 256 blocks, 32 rows x 1024 cols each
        size_t blk = blockIdx.y * 16 + blockIdx.x;
        const float4* src = (const float4*)(x + blk * 32768);
        bf16x4* dst = (bf16x4*)(((__bf16*)xb) + blk * 32768);
        #pragma unroll
        for (int u = 0; u < 32; ++u) {
            float4 v = src[u * 256 + t];
            dst[u * 256 + t] =
                (bf16x4){(__bf16)v.x, (__bf16)v.y, (__bf16)v.z, (__bf16)v.w};
        }
        return;
    }

    const float* src = (z == 0) ? Wq : (z == 1) ? Wk : (z == 2) ? Wv : Wo;
    __bf16* dst = (z < 3) ? (WT + (size_t)z * 1048576) : WoT;

    int r0 = blockIdx.y * 64, c0 = blockIdx.x * 64;
    int rr = t >> 2, cg = (t & 3) * 16;

    #pragma unroll
    for (int u = 0; u < 4; ++u) {
        float4 v = *(const float4*)(src + (size_t)(r0 + rr) * 1024 + c0 + cg + u * 4);
        tile[rr][cg + u * 4 + 0] = v.x;
        tile[rr][cg + u * 4 + 1] = v.y;
        tile[rr][cg + u * 4 + 2] = v.z;
        tile[rr][cg + u * 4 + 3] = v.w;
    }
    __syncthreads();
    bf16x8 o0, o1;
    #pragma unroll
    for (int jj = 0; jj < 8; ++jj) o0[jj] = (__bf16)tile[cg + jj][rr];
    #pragma unroll
    for (int jj = 0; jj < 8; ++jj) o1[jj] = (__bf16)tile[cg + 8 + jj][rr];
    __bf16* dp = dst + (size_t)(c0 + rr) * 1024 + r0 + cg;
    *(bf16x8*)dp = o0;
    *(bf16x8*)(dp + 8) = o1;
}

// ---------------------------------------------------------------------------
// bf16 MFMA GEMM, C = A(MxK) * Bt(NxK)^T.
// Deep-pipelined template (T2+T3+T4+T5): BM=256, BN=128, BK=64, 512 thr
// (8 waves, WARPS_M=4 x WARPS_N=2, 64x64 output per wave).
// - global_load_lds staging, 2 K-tile LDS slots; tile i+1's 6 DMAs issued at
//   phase A of iter i -> a FULL iteration of compute covers them.
// - raw s_barrier only; one `s_waitcnt vmcnt` per K-tile (counted at iter 0,
//   fully-covered drain afterwards). No __syncthreads drain in the loop.
// - LDS XOR swizzle byte ^= ((row&7)<<4): linear LDS dest, inverse-swizzled
//   per-lane GLOBAL source (rule 21), swizzled ds_read addrs -> conflict-free.
// - s_setprio(1) around each 16-MFMA cluster; 2 phases per K-tile (mi-halves),
//   B-fragments held in registers across both phases.
// mode 0: QKV epilogue (Q pre-scaled by log2e/8); mode 1: fp32 out + bias.
// ---------------------------------------------------------------------------
__global__ __launch_bounds__(512, 2) void gemm_bt(
    const __bf16* __restrict__ A, const __bf16* __restrict__ Bt, int mode,
    __bf16* __restrict__ qb, __bf16* __restrict__ kb, __bf16* __restrict__ vb,
    const float* __restrict__ bq, const float* __restrict__ bk,
    const float* __restrict__ bv,
    float* __restrict__ outf, const float* __restrict__ bo)
{
    __shared__ __align__(16) __bf16 As[2][256][64];   // 64 KB
    __shared__ __align__(16) __bf16 Bs[2][128][64];   // 32 KB

    const int t = threadIdx.x;
    const int wave = t >> 6, lane = t & 63;
    const int quad = lane >> 4, l16 = lane & 15;
    const int wm = wave >> 1, wn = wave & 1;          // 4 x 2 waves
    const int m0 = blockIdx.y * 256, n0 = blockIdx.x * 128;

    // Staging: thread t covers row (u*64 + t>>3), 16B chunk (t&7) of each
    // 64-row half. Global col pre-swizzled so that linear LDS slot (row, cb)
    // holds global data (row, cb ^ ((row&7)<<4)).
    const int srow = t >> 3;                              // 0..63
    const int scol = (((t & 7) ^ ((t >> 3) & 7)) * 8);    // elems, 0..56
    const __bf16* pa = A  + (size_t)(m0 + srow) * 1024 + scol;
    const __bf16* pb = Bt + (size_t)(n0 + srow) * 1024 + scol;
    char* lA = (char*)(&As[0][0][0]) + t * 16;
    char* lB = (char*)(&Bs[0][0][0]) + t * 16;

#define STAGE(slot, k0) do {                                   \
        gll16(pa + (k0),           lA + (slot) * 32768);       \
        gll16(pa + (k0) +  65536,  lA + (slot) * 32768 +  8192); \
        gll16(pa + (k0) + 131072,  lA + (slot) * 32768 + 16384); \
        gll16(pa + (k0) + 196608,  lA + (slot) * 32768 + 24576); \
        gll16(pb + (k0),           lB + (slot) * 16384);       \
        gll16(pb + (k0) +  65536,  lB + (slot) * 16384 +  8192); \
    } while (0)

    STAGE(0, 0);     // tile 0 -> slot 0 (issued ASAP)
    STAGE(1, 64);    // tile 1 -> slot 1

    f32x4 acc[4][4];
    #pragma unroll
    for (int i = 0; i < 4; ++i)
        #pragma unroll
        for (int j = 0; j < 4; ++j) acc[i][j] = (f32x4){0.f, 0.f, 0.f, 0.f};

    const int swz = (l16 & 7) << 4;   // read-side XOR (row&7 == l16&7)

    for (int it = 0; it < 16; ++it) {
        const int s = it & 1;
        // K-tile boundary: my DMAs for tile `it` landed; + barrier => ALL
        // waves' DMAs landed and all reads of slot s^1 are done.
        if (it == 0) asm volatile("s_waitcnt vmcnt(6)" ::: "memory");
        else         asm volatile("s_waitcnt vmcnt(0)" ::: "memory");
        __builtin_amdgcn_s_barrier();

        // Issue tile it+1 into slot s^1 (free since end of iter it-1);
        // waited at the NEXT boundary -> ~1 full iter of cover.
        if (it >= 1 && it < 15) STAGE(s ^ 1, (it + 1) * 64);

        const char* baseA = (const char*)&As[s][0][0];
        const char* baseB = (const char*)&Bs[s][0][0];

        // B-fragments for all 4 nj, both k-slices; live across both phases.
        bf16x8 bfrag[2][4];
        #pragma unroll
        for (int nj = 0; nj < 4; ++nj) {
            int rowb = (wn * 64 + nj * 16 + l16) * 128;
            bfrag[0][nj] = *(const bf16x8*)(baseB + rowb + ((quad * 16) ^ swz));
            bfrag[1][nj] = *(const bf16x8*)(baseB + rowb + ((64 + quad * 16) ^ swz));
        }

        // ---- phase A: mi 0,1 ----
        {
            bf16x8 afr[2][2];
            #pragma unroll
            for (int mi = 0; mi < 2; ++mi) {
                int rowa = (wm * 64 + mi * 16 + l16) * 128;
                afr[mi][0] = *(const bf16x8*)(baseA + rowa + ((quad * 16) ^ swz));
                afr[mi][1] = *(const bf16x8*)(baseA + rowa + ((64 + quad * 16) ^ swz));
            }
            __builtin_amdgcn_s_setprio(1);
            #pragma unroll
            for (int mi = 0; mi < 2; ++mi)
                #pragma unroll
                for (int nj = 0; nj < 4; ++nj)
                    acc[mi][nj] = MFMA16(afr[mi][1], bfrag[1][nj],
                                  MFMA16(afr[mi][0], bfrag[0][nj], acc[mi][nj]));
            __builtin_amdgcn_s_setprio(0);
        }
        __builtin_amdgcn_s_barrier();   // rhythm barrier (no hazard)

        // ---- phase B: mi 2,3 ----
        {
            bf16x8 afr[2][2];
            #pragma unroll
            for (int mi = 0; mi < 2; ++mi) {
                int rowa = (wm * 64 + (mi + 2) * 16 + l16) * 128;
                afr[mi][0] = *(const bf16x8*)(baseA + rowa + ((quad * 16) ^ swz));
                afr[mi][1] = *(const bf16x8*)(baseA + rowa + ((64 + quad * 16) ^ swz));
            }
            __builtin_amdgcn_s_setprio(1);
            #pragma unroll
            for (int mi = 0; mi < 2; ++mi)
                #pragma unroll
                for (int nj = 0; nj < 4; ++nj)
                    acc[mi + 2][nj] = MFMA16(afr[mi][1], bfrag[1][nj],
                                      MFMA16(afr[mi][0], bfrag[0][nj], acc[mi + 2][nj]));
            __builtin_amdgcn_s_setprio(0);
        }
    }
#undef STAGE

    if (mode == 0) {
        const int z = n0 >> 10;
        const float* bias = (z == 0) ? bq : (z == 1) ? bk : bv;
        // Q scale: (1/8) * log2(e) so attn can use raw v_exp_f32 (2^x).
        const float sc2 = (z == 0) ? 0.18033688011112042f : 1.0f;
        #pragma unroll
        for (int mi = 0; mi < 4; ++mi) {
            int row = m0 + wm * 64 + mi * 16 + quad * 4;
            int b = row >> 10, sx = row & 1023;
            #pragma unroll
            for (int nj = 0; nj < 4; ++nj) {
                int n1 = (n0 + wn * 64 + nj * 16 + l16) & 1023;
                int h = n1 >> 6, ch = n1 & 63;
                float bia = bias[n1];
                if (z < 2) {
                    __bf16* dst = ((z == 0) ? qb : kb)
                        + ((size_t)(b * Hh + h) * Ss + sx) * Kk + ch;
                    #pragma unroll
                    for (int r = 0; r < 4; ++r)
                        dst[(size_t)r * Kk] = (__bf16)((acc[mi][nj][r] + bia) * sc2);
                } else {
                    bf16x4 o;
                    #pragma unroll
                    for (int r = 0; r < 4; ++r) o[r] = (__bf16)(acc[mi][nj][r] + bia);
                    *(bf16x4*)(vb + ((size_t)(b * Hh + h) * Kk + ch) * Ss + sx) = o;
                }
            }
        }
    } else {
        #pragma unroll
        for (int mi = 0; mi < 4; ++mi) {
            int row = m0 + wm * 64 + mi * 16 + quad * 4;
            #pragma unroll
            for (int nj = 0; nj < 4; ++nj) {
                int n = n0 + wn * 64 + nj * 16 + l16;
                float bia = bo[n];
                #pragma unroll
                for (int r = 0; r < 4; ++r)
                    outf[(size_t)(row + r) * 1024 + n] = acc[mi][nj][r] + bia;
            }
        }
    }
}

// ---------------------------------------------------------------------------
// Flash attention: fixed-base softmax (scores bounded => no max tracking),
// wave-private P (no barrier), 32 q/wave, VGPR prefetch of next K/V tile,
// ping-pong K/V LDS (one barrier per tile), exp2 softmax, setprio on MFMA.
// Mask: p = mq ? (mk ? exp(s) : 0) : 1 — exactly matches reference semantics.
// ---------------------------------------------------------------------------
__global__ __launch_bounds__(256) void attn(
    const __bf16* __restrict__ qb, const __bf16* __restrict__ kb,
    const __bf16* __restrict__ vb, const int* __restrict__ mask,
    __bf16* __restrict__ ctx)
{
    const int bh = blockIdx.x;
    const int q0 = blockIdx.y * 128;
    const int b  = bh >> 4;
    const int h  = bh & 15;
    const size_t base = (size_t)bh * Ss * Kk;

    __shared__ __align__(16) __bf16 Qs[128][72];
    __shared__ __align__(16) __bf16 Ks[2][64][72];
    __shared__ __align__(16) __bf16 VTs[2][64][72];
    __shared__ __align__(16) __bf16 Ps[4][32][72];
    __shared__ float mkf[1024];

    const int t    = threadIdx.x;
    const int wave = t >> 6, lane = t & 63;
    const int quad = lane >> 4, l16 = lane & 15;
    const int qbase = wave * 32;

    #pragma unroll
    for (int p = 0; p < 4; ++p) {
        int idx = t + p * 256;
        int r = idx >> 3, g = idx & 7;
        *(bf16x8*)&Qs[r][g * 8] =
            *(const bf16x8*)(qb + base + (size_t)(q0 + r) * Kk + g * 8);
    }
    {
        int4 mi = *(const int4*)(mask + b * Ss + t * 4);
        mkf[t * 4 + 0] = (float)mi.x;
        mkf[t * 4 + 1] = (float)mi.y;
        mkf[t * 4 + 2] = (float)mi.z;
        mkf[t * 4 + 3] = (float)mi.w;
    }

    const int r0 = t >> 3, c0 = (t & 7) * 8;
    bf16x8 kr0, kr1, vr0, vr1;
    kr0 = *(const bf16x8*)(kb + base + (size_t)(r0) * Kk + c0);
    kr1 = *(const bf16x8*)(kb + base + (size_t)(r0 + 32) * Kk + c0);
    vr0 = *(const bf16x8*)(vb + base + (size_t)(r0) * Ss + c0);
    vr1 = *(const bf16x8*)(vb + base + (size_t)(r0 + 32) * Ss + c0);

    __syncthreads();   // Qs + mkf visible

    bf16x8 aq[2][2];
    #pragma unroll
    for (int rg = 0; rg < 2; ++rg) {
        aq[rg][0] = *(const bf16x8*)&Qs[qbase + rg * 16 + l16][quad * 8];
        aq[rg][1] = *(const bf16x8*)&Qs[qbase + rg * 16 + l16][32 + quad * 8];
    }
    float mqf[2][4], omqf[2][4];
    #pragma unroll
    for (int rg = 0; rg < 2; ++rg)
        #pragma unroll
        for (int i = 0; i < 4; ++i) {
            float m = mkf[q0 + qbase + rg * 16 + quad * 4 + i];
            mqf[rg][i] = m; omqf[rg][i] = 1.0f - m;
        }

    f32x4 O[2][4];
    float lsum[2][4];
    #pragma unroll
    for (int rg = 0; rg < 2; ++rg)
        #pragma unroll
        for (int nb = 0; nb < 4; ++nb) O[rg][nb] = (f32x4){0.f, 0.f, 0.f, 0.f};
    #pragma unroll
    for (int rg = 0; rg < 2; ++rg)
        #pragma unroll
        for (int i = 0; i < 4; ++i) lsum[rg][i] = 0.f;

    for (int kt = 0; kt < Ss; kt += 64) {
        const int p = (kt >> 6) & 1;
        *(bf16x8*)&Ks[p][r0][c0] = kr0;
        *(bf16x8*)&Ks[p][r0 + 32][c0] = kr1;
        *(bf16x8*)&VTs[p][r0][c0] = vr0;
        *(bf16x8*)&VTs[p][r0 + 32][c0] = vr1;
        __syncthreads();   // the ONLY barrier per tile

        int ktn = kt + 64;
        if (ktn < Ss) {    // issue next tile's loads; in flight across compute
            kr0 = *(const bf16x8*)(kb + base + (size_t)(ktn + r0) * Kk + c0);
            kr1 = *(const bf16x8*)(kb + base + (size_t)(ktn + r0 + 32) * Kk + c0);
            vr0 = *(const bf16x8*)(vb + base + (size_t)(r0) * Ss + ktn + c0);
            vr1 = *(const bf16x8*)(vb + base + (size_t)(r0 + 32) * Ss + ktn + c0);
        }

        float mkv[4];
        #pragma unroll
        for (int nb = 0; nb < 4; ++nb) mkv[nb] = mkf[kt + nb * 16 + l16];

        bf16x8 kb0[4], kb1[4];
        #pragma unroll
        for (int nb = 0; nb < 4; ++nb) {
            kb0[nb] = *(const bf16x8*)&Ks[p][nb * 16 + l16][quad * 8];
            kb1[nb] = *(const bf16x8*)&Ks[p][nb * 16 + l16][32 + quad * 8];
        }

        f32x4 s[2][4];
        __builtin_amdgcn_s_setprio(1);
        #pragma unroll
        for (int rg = 0; rg < 2; ++rg)
            #pragma unroll
            for (int nb = 0; nb < 4; ++nb) {
                f32x4 a = (f32x4){0.f, 0.f, 0.f, 0.f};
                a = MFMA16(aq[rg][0], kb0[nb], a);
                a = MFMA16(aq[rg][1], kb1[nb], a);
                s[rg][nb] = a;
            }
        __builtin_amdgcn_s_setprio(0);

        #pragma unroll
        for (int rg = 0; rg < 2; ++rg)
            #pragma unroll
            for (int i = 0; i < 4; ++i) {
                float ls = 0.f;
                #pragma unroll
                for (int nb = 0; nb < 4; ++nb) {
                    float pv = exp2_hw(s[rg][nb][i]) * mkv[nb];
                    pv = pv * mqf[rg][i] + omqf[rg][i];
                    Ps[wave][rg * 16 + quad * 4 + i][nb * 16 + l16] = (__bf16)pv;
                    ls += pv;
                }
                lsum[rg][i] += ls;
            }

        bf16x8 ap0[2], ap1[2];
        #pragma unroll
        for (int rg = 0; rg < 2; ++rg) {
            ap0[rg] = *(const bf16x8*)&Ps[wave][rg * 16 + l16][quad * 8];
            ap1[rg] = *(const bf16x8*)&Ps[wave][rg * 16 + l16][32 + quad * 8];
        }
        __builtin_amdgcn_s_setprio(1);
        #pragma unroll
        for (int nb = 0; nb < 4; ++nb) {
            bf16x8 vb0 = *(const bf16x8*)&VTs[p][nb * 16 + l16][quad * 8];
            bf16x8 vb1 = *(const bf16x8*)&VTs[p][nb * 16 + l16][32 + quad * 8];
            #pragma unroll
            for (int rg = 0; rg < 2; ++rg) {
                O[rg][nb] = MFMA16(ap0[rg], vb0, O[rg][nb]);
                O[rg][nb] = MFMA16(ap1[rg], vb1, O[rg][nb]);
            }
        }
        __builtin_amdgcn_s_setprio(0);
    }

    #pragma unroll
    for (int rg = 0; rg < 2; ++rg)
        #pragma unroll
        for (int i = 0; i < 4; ++i) {
            float l = lsum[rg][i];
            l += __shfl_xor(l, 1);
            l += __shfl_xor(l, 2);
            l += __shfl_xor(l, 4);
            l += __shfl_xor(l, 8);
            float inv = 1.0f / l;
            int srow = q0 + qbase + rg * 16 + quad * 4 + i;
            __bf16* dst = ctx + ((size_t)(b * Ss + srow) * Hh + h) * Kk;
            #pragma unroll
            for (int nb = 0; nb < 4; ++nb)
                dst[nb * 16 + l16] = (__bf16)(O[rg][nb][i] * inv);
        }
}

extern "C" void kernel_launch(void* const* d_in, const int* in_sizes, int n_in,
                              void* d_out, int out_size, void* d_ws, size_t ws_size,
                              hipStream_t stream) {
    const float* x    = (const float*)d_in[0];
    const int*   mask = (const int*)d_in[1];
    const float* Wq   = (const float*)d_in[2];
    const float* bq   = (const float*)d_in[3];
    const float* Wk   = (const float*)d_in[4];
    const float* bk   = (const float*)d_in[5];
    const float* Wv   = (const float*)d_in[6];
    const float* bv   = (const float*)d_in[7];
    const float* Wo   = (const float*)d_in[8];
    const float* bo   = (const float*)d_in[9];

    __bf16* xb   = (__bf16*)d_ws;
    __bf16* WT   = xb + XB_E;
    __bf16* WoT  = WT + WT_E;
    __bf16* qb   = WoT + WOT_E;
    __bf16* kb   = qb + QKV_E;
    __bf16* vb   = kb + QKV_E;
    __bf16* ctxb = vb + QKV_E;
    float* out = (float*)d_out;

    prep<<<dim3(16, 16, 5), 256, 0, stream>>>(x, Wq, Wk, Wv, Wo, xb, WT, WoT);
    gemm_bt<<<dim3(24, 32), 512, 0, stream>>>(xb, WT, 0, qb, kb, vb,
                                              bq, bk, bv, nullptr, nullptr);
    attn<<<dim3(128, 8), 256, 0, stream>>>(qb, kb, vb, mask, ctxb);
    gemm_bt<<<dim3(8, 32), 512, 0, stream>>>(ctxb, WoT, 1, nullptr, nullptr,
                                             nullptr, nullptr, nullptr, nullptr,
                                             out, bo);
}

// Round 4
// 274.609 us; speedup vs baseline: 1.0172x; 1.0172x over previous
//
#include <hip/hip_runtime.h>
#include <math.h>

#define Ss 1024
#define Dd 1024
#define Hh 16
#define Kk 64

typedef __bf16 bf16x8 __attribute__((ext_vector_type(8)));
typedef __bf16 bf16x4 __attribute__((ext_vector_type(4)));
typedef float  f32x4  __attribute__((ext_vector_type(4)));

#define MFMA16(a, b, c) __builtin_amdgcn_mfma_f32_16x16x32_bf16(a, b, c, 0, 0, 0)

// ws element offsets (bf16 units)
#define XB_E   8388608u
#define WT_E   3145728u
#define WOT_E  1048576u
#define QKV_E  8388608u

// v_exp_f32 is natively 2^x; log2(e) is folded into the Q scale in gemm.
__device__ __forceinline__ float exp2_hw(float x) {
    float r; asm("v_exp_f32 %0, %1" : "=v"(r) : "v"(x)); return r;
}

// global -> LDS DMA, 16B per lane. LDS dest: wave-uniform base + lane*16.
typedef __attribute__((address_space(1))) const void gas_void;
typedef __attribute__((address_space(3))) void las_void;
__device__ __forceinline__ void gll16(const __bf16* g, char* l) {
    __builtin_amdgcn_global_load_lds((gas_void*)g, (las_void*)l, 16, 0, 0);
}

// ---------------------------------------------------------------------------
// prep: z<4 -> transpose+cast weight matrix z; z==4 -> cast x to bf16
// ---------------------------------------------------------------------------
__global__ __launch_bounds__(256) void prep(
    const float* __restrict__ x,
    const float* __restrict__ Wq, const float* __restrict__ Wk,
    const float* __restrict__ Wv, const float* __restrict__ Wo,
    __bf16* __restrict__ xb, __bf16* __restrict__ WT, __bf16* __restrict__ WoT)
{
    __shared__ float tile[64][65];
    const int z = blockIdx.z;
    const int t = threadIdx.x;

    if (z == 4) {   // x cast: 256 blocks, 32 rows x 1024 cols each
        size_t blk = blockIdx.y * 16 + blockIdx.x;
        const float4* src = (const float4*)(x + blk * 32768);
        bf16x4* dst = (bf16x4*)(((__bf16*)xb) + blk * 32768);
        #pragma unroll
        for (int u = 0; u < 32; ++u) {
            float4 v = src[u * 256 + t];
            dst[u * 256 + t] =
                (bf16x4){(__bf16)v.x, (__bf16)v.y, (__bf16)v.z, (__bf16)v.w};
        }
        return;
    }

    const float* src = (z == 0) ? Wq : (z == 1) ? Wk : (z == 2) ? Wv : Wo;
    __bf16* dst = (z < 3) ? (WT + (size_t)z * 1048576) : WoT;

    int r0 = blockIdx.y * 64, c0 = blockIdx.x * 64;
    int rr = t >> 2, cg = (t & 3) * 16;

    #pragma unroll
    for (int u = 0; u < 4; ++u) {
        float4 v = *(const float4*)(src + (size_t)(r0 + rr) * 1024 + c0 + cg + u * 4);
        tile[rr][cg + u * 4 + 0] = v.x;
        tile[rr][cg + u * 4 + 1] = v.y;
        tile[rr][cg + u * 4 + 2] = v.z;
        tile[rr][cg + u * 4 + 3] = v.w;
    }
    __syncthreads();
    bf16x8 o0, o1;
    #pragma unroll
    for (int jj = 0; jj < 8; ++jj) o0[jj] = (__bf16)tile[cg + jj][rr];
    #pragma unroll
    for (int jj = 0; jj < 8; ++jj) o1[jj] = (__bf16)tile[cg + 8 + jj][rr];
    __bf16* dp = dst + (size_t)(c0 + rr) * 1024 + r0 + cg;
    *(bf16x8*)dp = o0;
    *(bf16x8*)(dp + 8) = o1;
}

// ---------------------------------------------------------------------------
// bf16 MFMA GEMM, C = A(MxK) * Bt(NxK)^T.
// Deep-pipelined template (T2+T3+T4+T5): BM=256, BN=128, BK=64, 512 thr
// (8 waves, 4x2), 64x64 output per wave.
// T4 (this round): 3-slot LDS rotation, tile it+2 issued at iter it (2 full
// iters of cover), steady-state `s_waitcnt vmcnt(6)` at each boundary — the
// next tile's 6 DMAs stay IN FLIGHT across the barrier; vmcnt(0) only at the
// last iter. Per-wave ledger: prologue t0,t1 -> 12 outstanding; each iter
// wait(6) retires exactly the compute tile's 6; iters 0..13 stage tiles 2..15.
// Slot hazard: slot (it+2)%3's last readers were iter it-1, whose ds_reads
// complete before iter it's barrier; STAGE issued after that barrier.
// T2: XOR swizzle byte ^= ((row&7)<<4), linear LDS dest + inverse-swizzled
// per-lane global source + swizzled ds_read addrs (conflicts measured 0).
// T5: setprio(1) around each 16-MFMA cluster; 2 phases/K-tile, B-frags in
// regs across both phases, mid-phase rhythm barrier.
// mode 0: QKV epilogue (Q pre-scaled by log2e/8); mode 1: fp32 out + bias.
// ---------------------------------------------------------------------------
__global__ __launch_bounds__(512, 2) void gemm_bt(
    const __bf16* __restrict__ A, const __bf16* __restrict__ Bt, int mode,
    __bf16* __restrict__ qb, __bf16* __restrict__ kb, __bf16* __restrict__ vb,
    const float* __restrict__ bq, const float* __restrict__ bk,
    const float* __restrict__ bv,
    float* __restrict__ outf, const float* __restrict__ bo)
{
    __shared__ __align__(16) __bf16 As[3][256][64];   // 96 KB
    __shared__ __align__(16) __bf16 Bs[3][128][64];   // 48 KB

    const int t = threadIdx.x;
    const int wave = t >> 6, lane = t & 63;
    const int quad = lane >> 4, l16 = lane & 15;
    const int wm = wave >> 1, wn = wave & 1;          // 4 x 2 waves
    const int m0 = blockIdx.y * 256, n0 = blockIdx.x * 128;

    // Staging: thread t covers row (u*64 + t>>3), 16B chunk (t&7) of each
    // 64-row half. Global col pre-swizzled so that linear LDS slot (row, cb)
    // holds global data (row, cb ^ ((row&7)<<4)).
    const int srow = t >> 3;                              // 0..63
    const int scol = (((t & 7) ^ ((t >> 3) & 7)) * 8);    // elems, 0..56
    const __bf16* pa = A  + (size_t)(m0 + srow) * 1024 + scol;
    const __bf16* pb = Bt + (size_t)(n0 + srow) * 1024 + scol;
    char* lA = (char*)(&As[0][0][0]) + t * 16;
    char* lB = (char*)(&Bs[0][0][0]) + t * 16;

#define STAGE(slot, k0) do {                                   \
        gll16(pa + (k0),           lA + (slot) * 32768);       \
        gll16(pa + (k0) +  65536,  lA + (slot) * 32768 +  8192); \
        gll16(pa + (k0) + 131072,  lA + (slot) * 32768 + 16384); \
        gll16(pa + (k0) + 196608,  lA + (slot) * 32768 + 24576); \
        gll16(pb + (k0),           lB + (slot) * 16384);       \
        gll16(pb + (k0) +  65536,  lB + (slot) * 16384 +  8192); \
    } while (0)

    STAGE(0, 0);     // tile 0 -> slot 0
    STAGE(1, 64);    // tile 1 -> slot 1

    f32x4 acc[4][4];
    #pragma unroll
    for (int i = 0; i < 4; ++i)
        #pragma unroll
        for (int j = 0; j < 4; ++j) acc[i][j] = (f32x4){0.f, 0.f, 0.f, 0.f};

    const int swz = (l16 & 7) << 4;   // read-side XOR (row&7 == l16&7)

    int slot = 0;
    for (int it = 0; it < 16; ++it) {
        // Retire ONLY the compute tile's 6 DMAs; keep the next tile's 6 in
        // flight across the barrier (T4). Drain fully only at the last iter.
        if (it == 15) asm volatile("s_waitcnt vmcnt(0)" ::: "memory");
        else          asm volatile("s_waitcnt vmcnt(6)" ::: "memory");
        __builtin_amdgcn_s_barrier();

        if (it < 14) {
            int ws = slot + 2; if (ws >= 3) ws -= 3;
            STAGE(ws, (it + 2) * 64);
        }

        const char* baseA = (const char*)&As[slot][0][0];
        const char* baseB = (const char*)&Bs[slot][0][0];

        // B-fragments for all 4 nj, both k-slices; live across both phases.
        bf16x8 bfrag[2][4];
        #pragma unroll
        for (int nj = 0; nj < 4; ++nj) {
            int rowb = (wn * 64 + nj * 16 + l16) * 128;
            bfrag[0][nj] = *(const bf16x8*)(baseB + rowb + ((quad * 16) ^ swz));
            bfrag[1][nj] = *(const bf16x8*)(baseB + rowb + ((64 + quad * 16) ^ swz));
        }

        // ---- phase A: mi 0,1 ----
        {
            bf16x8 afr[2][2];
            #pragma unroll
            for (int mi = 0; mi < 2; ++mi) {
                int rowa = (wm * 64 + mi * 16 + l16) * 128;
                afr[mi][0] = *(const bf16x8*)(baseA + rowa + ((quad * 16) ^ swz));
                afr[mi][1] = *(const bf16x8*)(baseA + rowa + ((64 + quad * 16) ^ swz));
            }
            __builtin_amdgcn_s_setprio(1);
            #pragma unroll
            for (int mi = 0; mi < 2; ++mi)
                #pragma unroll
                for (int nj = 0; nj < 4; ++nj)
                    acc[mi][nj] = MFMA16(afr[mi][1], bfrag[1][nj],
                                  MFMA16(afr[mi][0], bfrag[0][nj], acc[mi][nj]));
            __builtin_amdgcn_s_setprio(0);
        }
        __builtin_amdgcn_s_barrier();   // rhythm barrier (no hazard)

        // ---- phase B: mi 2,3 ----
        {
            bf16x8 afr[2][2];
            #pragma unroll
            for (int mi = 0; mi < 2; ++mi) {
                int rowa = (wm * 64 + (mi + 2) * 16 + l16) * 128;
                afr[mi][0] = *(const bf16x8*)(baseA + rowa + ((quad * 16) ^ swz));
                afr[mi][1] = *(const bf16x8*)(baseA + rowa + ((64 + quad * 16) ^ swz));
            }
            __builtin_amdgcn_s_setprio(1);
            #pragma unroll
            for (int mi = 0; mi < 2; ++mi)
                #pragma unroll
                for (int nj = 0; nj < 4; ++nj)
                    acc[mi + 2][nj] = MFMA16(afr[mi][1], bfrag[1][nj],
                                      MFMA16(afr[mi][0], bfrag[0][nj], acc[mi + 2][nj]));
            __builtin_amdgcn_s_setprio(0);
        }

        ++slot; if (slot == 3) slot = 0;
    }
#undef STAGE

    if (mode == 0) {
        const int z = n0 >> 10;
        const float* bias = (z == 0) ? bq : (z == 1) ? bk : bv;
        // Q scale: (1/8) * log2(e) so attn can use raw v_exp_f32 (2^x).
        const float sc2 = (z == 0) ? 0.18033688011112042f : 1.0f;
        #pragma unroll
        for (int mi = 0; mi < 4; ++mi) {
            int row = m0 + wm * 64 + mi * 16 + quad * 4;
            int b = row >> 10, sx = row & 1023;
            #pragma unroll
            for (int nj = 0; nj < 4; ++nj) {
                int n1 = (n0 + wn * 64 + nj * 16 + l16) & 1023;
                int h = n1 >> 6, ch = n1 & 63;
                float bia = bias[n1];
                if (z < 2) {
                    __bf16* dst = ((z == 0) ? qb : kb)
                        + ((size_t)(b * Hh + h) * Ss + sx) * Kk + ch;
                    #pragma unroll
                    for (int r = 0; r < 4; ++r)
                        dst[(size_t)r * Kk] = (__bf16)((acc[mi][nj][r] + bia) * sc2);
                } else {
                    bf16x4 o;
                    #pragma unroll
                    for (int r = 0; r < 4; ++r) o[r] = (__bf16)(acc[mi][nj][r] + bia);
                    *(bf16x4*)(vb + ((size_t)(b * Hh + h) * Kk + ch) * Ss + sx) = o;
                }
            }
        }
    } else {
        #pragma unroll
        for (int mi = 0; mi < 4; ++mi) {
            int row = m0 + wm * 64 + mi * 16 + quad * 4;
            #pragma unroll
            for (int nj = 0; nj < 4; ++nj) {
                int n = n0 + wn * 64 + nj * 16 + l16;
                float bia = bo[n];
                #pragma unroll
                for (int r = 0; r < 4; ++r)
                    outf[(size_t)(row + r) * 1024 + n] = acc[mi][nj][r] + bia;
            }
        }
    }
}

// ---------------------------------------------------------------------------
// Flash attention: fixed-base softmax (scores bounded => no max tracking),
// wave-private P (no barrier), 32 q/wave, VGPR prefetch of next K/V tile,
// ping-pong K/V LDS (one barrier per tile), exp2 softmax, setprio on MFMA.
// Mask: p = mq ? (mk ? exp(s) : 0) : 1 — exactly matches reference semantics.
// ---------------------------------------------------------------------------
__global__ __launch_bounds__(256) void attn(
    const __bf16* __restrict__ qb, const __bf16* __restrict__ kb,
    const __bf16* __restrict__ vb, const int* __restrict__ mask,
    __bf16* __restrict__ ctx)
{
    const int bh = blockIdx.x;
    const int q0 = blockIdx.y * 128;
    const int b  = bh >> 4;
    const int h  = bh & 15;
    const size_t base = (size_t)bh * Ss * Kk;

    __shared__ __align__(16) __bf16 Qs[128][72];
    __shared__ __align__(16) __bf16 Ks[2][64][72];
    __shared__ __align__(16) __bf16 VTs[2][64][72];
    __shared__ __align__(16) __bf16 Ps[4][32][72];
    __shared__ float mkf[1024];

    const int t    = threadIdx.x;
    const int wave = t >> 6, lane = t & 63;
    const int quad = lane >> 4, l16 = lane & 15;
    const int qbase = wave * 32;

    #pragma unroll
    for (int p = 0; p < 4; ++p) {
        int idx = t + p * 256;
        int r = idx >> 3, g = idx & 7;
        *(bf16x8*)&Qs[r][g * 8] =
            *(const bf16x8*)(qb + base + (size_t)(q0 + r) * Kk + g * 8);
    }
    {
        int4 mi = *(const int4*)(mask + b * Ss + t * 4);
        mkf[t * 4 + 0] = (float)mi.x;
        mkf[t * 4 + 1] = (float)mi.y;
        mkf[t * 4 + 2] = (float)mi.z;
        mkf[t * 4 + 3] = (float)mi.w;
    }

    const int r0 = t >> 3, c0 = (t & 7) * 8;
    bf16x8 kr0, kr1, vr0, vr1;
    kr0 = *(const bf16x8*)(kb + base + (size_t)(r0) * Kk + c0);
    kr1 = *(const bf16x8*)(kb + base + (size_t)(r0 + 32) * Kk + c0);
    vr0 = *(const bf16x8*)(vb + base + (size_t)(r0) * Ss + c0);
    vr1 = *(const bf16x8*)(vb + base + (size_t)(r0 + 32) * Ss + c0);

    __syncthreads();   // Qs + mkf visible

    bf16x8 aq[2][2];
    #pragma unroll
    for (int rg = 0; rg < 2; ++rg) {
        aq[rg][0] = *(const bf16x8*)&Qs[qbase + rg * 16 + l16][quad * 8];
        aq[rg][1] = *(const bf16x8*)&Qs[qbase + rg * 16 + l16][32 + quad * 8];
    }
    float mqf[2][4], omqf[2][4];
    #pragma unroll
    for (int rg = 0; rg < 2; ++rg)
        #pragma unroll
        for (int i = 0; i < 4; ++i) {
            float m = mkf[q0 + qbase + rg * 16 + quad * 4 + i];
            mqf[rg][i] = m; omqf[rg][i] = 1.0f - m;
        }

    f32x4 O[2][4];
    float lsum[2][4];
    #pragma unroll
    for (int rg = 0; rg < 2; ++rg)
        #pragma unroll
        for (int nb = 0; nb < 4; ++nb) O[rg][nb] = (f32x4){0.f, 0.f, 0.f, 0.f};
    #pragma unroll
    for (int rg = 0; rg < 2; ++rg)
        #pragma unroll
        for (int i = 0; i < 4; ++i) lsum[rg][i] = 0.f;

    for (int kt = 0; kt < Ss; kt += 64) {
        const int p = (kt >> 6) & 1;
        *(bf16x8*)&Ks[p][r0][c0] = kr0;
        *(bf16x8*)&Ks[p][r0 + 32][c0] = kr1;
        *(bf16x8*)&VTs[p][r0][c0] = vr0;
        *(bf16x8*)&VTs[p][r0 + 32][c0] = vr1;
        __syncthreads();   // the ONLY barrier per tile

        int ktn = kt + 64;
        if (ktn < Ss) {    // issue next tile's loads; in flight across compute
            kr0 = *(const bf16x8*)(kb + base + (size_t)(ktn + r0) * Kk + c0);
            kr1 = *(const bf16x8*)(kb + base + (size_t)(ktn + r0 + 32) * Kk + c0);
            vr0 = *(const bf16x8*)(vb + base + (size_t)(r0) * Ss + ktn + c0);
            vr1 = *(const bf16x8*)(vb + base + (size_t)(r0 + 32) * Ss + ktn + c0);
        }

        float mkv[4];
        #pragma unroll
        for (int nb = 0; nb < 4; ++nb) mkv[nb] = mkf[kt + nb * 16 + l16];

        bf16x8 kb0[4], kb1[4];
        #pragma unroll
        for (int nb = 0; nb < 4; ++nb) {
            kb0[nb] = *(const bf16x8*)&Ks[p][nb * 16 + l16][quad * 8];
            kb1[nb] = *(const bf16x8*)&Ks[p][nb * 16 + l16][32 + quad * 8];
        }

        f32x4 s[2][4];
        __builtin_amdgcn_s_setprio(1);
        #pragma unroll
        for (int rg = 0; rg < 2; ++rg)
            #pragma unroll
            for (int nb = 0; nb < 4; ++nb) {
                f32x4 a = (f32x4){0.f, 0.f, 0.f, 0.f};
                a = MFMA16(aq[rg][0], kb0[nb], a);
                a = MFMA16(aq[rg][1], kb1[nb], a);
                s[rg][nb] = a;
            }
        __builtin_amdgcn_s_setprio(0);

        #pragma unroll
        for (int rg = 0; rg < 2; ++rg)
            #pragma unroll
            for (int i = 0; i < 4; ++i) {
                float ls = 0.f;
                #pragma unroll
                for (int nb = 0; nb < 4; ++nb) {
                    float pv = exp2_hw(s[rg][nb][i]) * mkv[nb];
                    pv = pv * mqf[rg][i] + omqf[rg][i];
                    Ps[wave][rg * 16 + quad * 4 + i][nb * 16 + l16] = (__bf16)pv;
                    ls += pv;
                }
                lsum[rg][i] += ls;
            }

        bf16x8 ap0[2], ap1[2];
        #pragma unroll
        for (int rg = 0; rg < 2; ++rg) {
            ap0[rg] = *(const bf16x8*)&Ps[wave][rg * 16 + l16][quad * 8];
            ap1[rg] = *(const bf16x8*)&Ps[wave][rg * 16 + l16][32 + quad * 8];
        }
        __builtin_amdgcn_s_setprio(1);
        #pragma unroll
        for (int nb = 0; nb < 4; ++nb) {
            bf16x8 vb0 = *(const bf16x8*)&VTs[p][nb * 16 + l16][quad * 8];
            bf16x8 vb1 = *(const bf16x8*)&VTs[p][nb * 16 + l16][32 + quad * 8];
            #pragma unroll
            for (int rg = 0; rg < 2; ++rg) {
                O[rg][nb] = MFMA16(ap0[rg], vb0, O[rg][nb]);
                O[rg][nb] = MFMA16(ap1[rg], vb1, O[rg][nb]);
            }
        }
        __builtin_amdgcn_s_setprio(0);
    }

    #pragma unroll
    for (int rg = 0; rg < 2; ++rg)
        #pragma unroll
        for (int i = 0; i < 4; ++i) {
            float l = lsum[rg][i];
            l += __shfl_xor(l, 1);
            l += __shfl_xor(l, 2);
            l += __shfl_xor(l, 4);
            l += __shfl_xor(l, 8);
            float inv = 1.0f / l;
            int srow = q0 + qbase + rg * 16 + quad * 4 + i;
            __bf16* dst = ctx + ((size_t)(b * Ss + srow) * Hh + h) * Kk;
            #pragma unroll
            for (int nb = 0; nb < 4; ++nb)
                dst[nb * 16 + l16] = (__bf16)(O[rg][nb][i] * inv);
        }
}

extern "C" void kernel_launch(void* const* d_in, const int* in_sizes, int n_in,
                              void* d_out, int out_size, void* d_ws, size_t ws_size,
                              hipStream_t stream) {
    const float* x    = (const float*)d_in[0];
    const int*   mask = (const int*)d_in[1];
    const float* Wq   = (const float*)d_in[2];
    const float* bq   = (const float*)d_in[3];
    const float* Wk   = (const float*)d_in[4];
    const float* bk   = (const float*)d_in[5];
    const float* Wv   = (const float*)d_in[6];
    const float* bv   = (const float*)d_in[7];
    const float* Wo   = (const float*)d_in[8];
    const float* bo   = (const float*)d_in[9];

    __bf16* xb   = (__bf16*)d_ws;
    __bf16* WT   = xb + XB_E;
    __bf16* WoT  = WT + WT_E;
    __bf16* qb   = WoT + WOT_E;
    __bf16* kb   = qb + QKV_E;
    __bf16* vb   = kb + QKV_E;
    __bf16* ctxb = vb + QKV_E;
    float* out = (float*)d_out;

    prep<<<dim3(16, 16, 5), 256, 0, stream>>>(x, Wq, Wk, Wv, Wo, xb, WT, WoT);
    gemm_bt<<<dim3(24, 32), 512, 0, stream>>>(xb, WT, 0, qb, kb, vb,
                                              bq, bk, bv, nullptr, nullptr);
    attn<<<dim3(128, 8), 256, 0, stream>>>(qb, kb, vb, mask, ctxb);
    gemm_bt<<<dim3(8, 32), 512, 0, stream>>>(ctxb, WoT, 1, nullptr, nullptr,
                                             nullptr, nullptr, nullptr, nullptr,
                                             out, bo);
}

// Round 5
// 266.550 us; speedup vs baseline: 1.0480x; 1.0302x over previous
//
#include <hip/hip_runtime.h>
#include <math.h>

#define Ss 1024
#define Dd 1024
#define Hh 16
#define Kk 64

typedef __bf16 bf16x8 __attribute__((ext_vector_type(8)));
typedef __bf16 bf16x4 __attribute__((ext_vector_type(4)));
typedef float  f32x4  __attribute__((ext_vector_type(4)));

#define MFMA16(a, b, c) __builtin_amdgcn_mfma_f32_16x16x32_bf16(a, b, c, 0, 0, 0)

// ws element offsets (bf16 units)
#define XB_E   8388608u
#define WT_E   3145728u
#define WOT_E  1048576u
#define QKV_E  8388608u

// v_exp_f32 is natively 2^x; log2(e) is folded into the Q scale in gemm.
__device__ __forceinline__ float exp2_hw(float x) {
    float r; asm("v_exp_f32 %0, %1" : "=v"(r) : "v"(x)); return r;
}

// global -> LDS DMA, 16B per lane. LDS dest: wave-uniform base + lane*16.
typedef __attribute__((address_space(1))) const void gas_void;
typedef __attribute__((address_space(3))) void las_void;
__device__ __forceinline__ void gll16(const __bf16* g, char* l) {
    __builtin_amdgcn_global_load_lds((gas_void*)g, (las_void*)l, 16, 0, 0);
}

// ---------------------------------------------------------------------------
// prep: z<4 -> transpose+cast weight matrix z; z==4 -> cast x to bf16
// ---------------------------------------------------------------------------
__global__ __launch_bounds__(256) void prep(
    const float* __restrict__ x,
    const float* __restrict__ Wq, const float* __restrict__ Wk,
    const float* __restrict__ Wv, const float* __restrict__ Wo,
    __bf16* __restrict__ xb, __bf16* __restrict__ WT, __bf16* __restrict__ WoT)
{
    __shared__ float tile[64][65];
    const int z = blockIdx.z;
    const int t = threadIdx.x;

    if (z == 4) {   // x cast: 256 blocks, 32 rows x 1024 cols each
        size_t blk = blockIdx.y * 16 + blockIdx.x;
        const float4* src = (const float4*)(x + blk * 32768);
        bf16x4* dst = (bf16x4*)(((__bf16*)xb) + blk * 32768);
        #pragma unroll
        for (int u = 0; u < 32; ++u) {
            float4 v = src[u * 256 + t];
            dst[u * 256 + t] =
                (bf16x4){(__bf16)v.x, (__bf16)v.y, (__bf16)v.z, (__bf16)v.w};
        }
        return;
    }

    const float* src = (z == 0) ? Wq : (z == 1) ? Wk : (z == 2) ? Wv : Wo;
    __bf16* dst = (z < 3) ? (WT + (size_t)z * 1048576) : WoT;

    int r0 = blockIdx.y * 64, c0 = blockIdx.x * 64;
    int rr = t >> 2, cg = (t & 3) * 16;

    #pragma unroll
    for (int u = 0; u < 4; ++u) {
        float4 v = *(const float4*)(src + (size_t)(r0 + rr) * 1024 + c0 + cg + u * 4);
        tile[rr][cg + u * 4 + 0] = v.x;
        tile[rr][cg + u * 4 + 1] = v.y;
        tile[rr][cg + u * 4 + 2] = v.z;
        tile[rr][cg + u * 4 + 3] = v.w;
    }
    __syncthreads();
    bf16x8 o0, o1;
    #pragma unroll
    for (int jj = 0; jj < 8; ++jj) o0[jj] = (__bf16)tile[cg + jj][rr];
    #pragma unroll
    for (int jj = 0; jj < 8; ++jj) o1[jj] = (__bf16)tile[cg + 8 + jj][rr];
    __bf16* dp = dst + (size_t)(c0 + rr) * 1024 + r0 + cg;
    *(bf16x8*)dp = o0;
    *(bf16x8*)(dp + 8) = o1;
}

// ---------------------------------------------------------------------------
// bf16 MFMA GEMM, C = A(MxK) * Bt(NxK)^T.
// TRAFFIC-OPTIMIZED: 3 schedules (reg-staged / DMA+drain / DMA+counted-vmcnt)
// all measured ~84us => bound by L2-fill bandwidth (~7 TB/s demand), not
// scheduling. This version cuts fill traffic:
//  - BM=BN=256, BK=64 (m201 geometry): 8 waves (2Mx4N), 128x64 out per wave,
//    acc[8][4]. Fill bytes per output byte drop 1.5x vs 256x128.
//  - Bijective XCD swizzle (grids 384 & 128 blocks, both %8==0): each XCD
//    gets a contiguous x-fastest chunk -> A/B panels reused out of its L2.
// Pipeline: 2-slot LDS (128 KB), counted s_waitcnt vmcnt(8) at the boundary
// (tile i+1's 8 DMAs stay in flight across the barrier); tile i+2 staged
// after B3 (lgkmcnt(0)-drained barrier => all waves' slot-s reads done).
// mode 0: QKV epilogue (Q pre-scaled by log2e/8); mode 1: fp32 out + bias.
// ---------------------------------------------------------------------------
__global__ __launch_bounds__(512, 2) void gemm_bt(
    const __bf16* __restrict__ A, const __bf16* __restrict__ Bt, int mode,
    __bf16* __restrict__ qb, __bf16* __restrict__ kb, __bf16* __restrict__ vb,
    const float* __restrict__ bq, const float* __restrict__ bk,
    const float* __restrict__ bv,
    float* __restrict__ outf, const float* __restrict__ bo)
{
    __shared__ __align__(16) __bf16 As[2][256][64];   // 64 KB
    __shared__ __align__(16) __bf16 Bs[2][256][64];   // 64 KB

    const int t = threadIdx.x;
    const int wave = t >> 6, lane = t & 63;
    const int quad = lane >> 4, l16 = lane & 15;
    const int wm = wave >> 2, wn = wave & 3;          // 2 x 4 waves

    // Bijective XCD-aware swizzle: HW round-robins consecutive ids across
    // 8 XCDs; remap so XCD k owns a contiguous x-fastest chunk of tiles.
    const int nwg = gridDim.x * gridDim.y;
    const int cpx = nwg >> 3;                          // nwg % 8 == 0
    int g = blockIdx.y * gridDim.x + blockIdx.x;
    g = (g & 7) * cpx + (g >> 3);
    const int bx = g % gridDim.x, by = g / gridDim.x;
    const int m0 = by * 256, n0 = bx * 256;

    // Staging: thread t covers row (c*64 + t>>3), 16B chunk (t&7) of each
    // 64-row chunk. Global col pre-swizzled so linear LDS slot (row, cb)
    // holds global (row, cb ^ ((row&7)<<4)); row%8 == (t>>3)%8.
    const int srow = t >> 3;                              // 0..63
    const int scol = (((t & 7) ^ (srow & 7)) * 8);        // elems
    const __bf16* pa = A  + (size_t)(m0 + srow) * 1024 + scol;
    const __bf16* pb = Bt + (size_t)(n0 + srow) * 1024 + scol;
    char* lA = (char*)(&As[0][0][0]) + t * 16;
    char* lB = (char*)(&Bs[0][0][0]) + t * 16;

#define STAGE(slot, k0) do {                                     \
        gll16(pa + (k0),           lA + (slot) * 32768);         \
        gll16(pa + (k0) +  65536,  lA + (slot) * 32768 +  8192); \
        gll16(pa + (k0) + 131072,  lA + (slot) * 32768 + 16384); \
        gll16(pa + (k0) + 196608,  lA + (slot) * 32768 + 24576); \
        gll16(pb + (k0),           lB + (slot) * 32768);         \
        gll16(pb + (k0) +  65536,  lB + (slot) * 32768 +  8192); \
        gll16(pb + (k0) + 131072,  lB + (slot) * 32768 + 16384); \
        gll16(pb + (k0) + 196608,  lB + (slot) * 32768 + 24576); \
    } while (0)

    STAGE(0, 0);     // tile 0 -> slot 0   (8 DMAs/wave)
    STAGE(1, 64);    // tile 1 -> slot 1   (16 outstanding)

    f32x4 acc[8][4];
    #pragma unroll
    for (int i = 0; i < 8; ++i)
        #pragma unroll
        for (int j = 0; j < 4; ++j) acc[i][j] = (f32x4){0.f, 0.f, 0.f, 0.f};

    const int swz = (l16 & 7) << 4;   // read-side XOR (row&7 == l16&7)

    for (int it = 0; it < 16; ++it) {
        const int s = it & 1;
        // Retire ONLY tile it's 8 DMAs; tile it+1's 8 stay in flight across
        // the barrier. Each wave waits on its own; barrier makes all waves'
        // tile-it data visible. Drain fully only at the last iter.
        if (it == 15) asm volatile("s_waitcnt vmcnt(0)" ::: "memory");
        else          asm volatile("s_waitcnt vmcnt(8)" ::: "memory");
        __builtin_amdgcn_s_barrier();                 // B1

        const char* baseA = (const char*)&As[s][0][0];
        const char* baseB = (const char*)&Bs[s][0][0];

        // B-fragments: 4 nj x 2 k-slices, live across both phases.
        bf16x8 bfrag[2][4];
        #pragma unroll
        for (int nj = 0; nj < 4; ++nj) {
            int rowb = (wn * 64 + nj * 16 + l16) * 128;
            bfrag[0][nj] = *(const bf16x8*)(baseB + rowb + ((quad * 16) ^ swz));
            bfrag[1][nj] = *(const bf16x8*)(baseB + rowb + ((64 + quad * 16) ^ swz));
        }

        // ---- phase A: mi 0..3 ----
        {
            bf16x8 afr[4][2];
            #pragma unroll
            for (int mi = 0; mi < 4; ++mi) {
                int rowa = (wm * 128 + mi * 16 + l16) * 128;
                afr[mi][0] = *(const bf16x8*)(baseA + rowa + ((quad * 16) ^ swz));
                afr[mi][1] = *(const bf16x8*)(baseA + rowa + ((64 + quad * 16) ^ swz));
            }
            __builtin_amdgcn_s_setprio(1);
            #pragma unroll
            for (int mi = 0; mi < 4; ++mi)
                #pragma unroll
                for (int nj = 0; nj < 4; ++nj)
                    acc[mi][nj] = MFMA16(afr[mi][1], bfrag[1][nj],
                                  MFMA16(afr[mi][0], bfrag[0][nj], acc[mi][nj]));
            __builtin_amdgcn_s_setprio(0);
        }
        __builtin_amdgcn_s_barrier();                 // B2 (rhythm)

        // ---- phase B: mi 4..7 ----
        {
            bf16x8 afr[4][2];
            #pragma unroll
            for (int mi = 0; mi < 4; ++mi) {
                int rowa = (wm * 128 + (mi + 4) * 16 + l16) * 128;
                afr[mi][0] = *(const bf16x8*)(baseA + rowa + ((quad * 16) ^ swz));
                afr[mi][1] = *(const bf16x8*)(baseA + rowa + ((64 + quad * 16) ^ swz));
            }
            // All of this wave's slot-s ds_reads are now issued; drain them,
            // then B3 => no wave has pending reads of slot s => safe to DMA
            // tile it+2 into slot s while phase-B MFMAs (register-only) run.
            asm volatile("s_waitcnt lgkmcnt(0)" ::: "memory");
            __builtin_amdgcn_sched_barrier(0);
            __builtin_amdgcn_s_barrier();             // B3
            if (it < 14) STAGE(s, (it + 2) * 64);

            __builtin_amdgcn_s_setprio(1);
            #pragma unroll
            for (int mi = 0; mi < 4; ++mi)
                #pragma unroll
                for (int nj = 0; nj < 4; ++nj)
                    acc[mi + 4][nj] = MFMA16(afr[mi][1], bfrag[1][nj],
                                      MFMA16(afr[mi][0], bfrag[0][nj], acc[mi + 4][nj]));
            __builtin_amdgcn_s_setprio(0);
        }
    }
#undef STAGE

    if (mode == 0) {
        const int z = n0 >> 10;   // 256 | 1024 -> uniform per block
        const float* bias = (z == 0) ? bq : (z == 1) ? bk : bv;
        // Q scale: (1/8) * log2(e) so attn can use raw v_exp_f32 (2^x).
        const float sc2 = (z == 0) ? 0.18033688011112042f : 1.0f;
        #pragma unroll
        for (int mi = 0; mi < 8; ++mi) {
            int row = m0 + wm * 128 + mi * 16 + quad * 4;
            int b = row >> 10, sx = row & 1023;
            #pragma unroll
            for (int nj = 0; nj < 4; ++nj) {
                int n1 = (n0 + wn * 64 + nj * 16 + l16) & 1023;
                int h = n1 >> 6, ch = n1 & 63;
                float bia = bias[n1];
                if (z < 2) {
                    __bf16* dst = ((z == 0) ? qb : kb)
                        + ((size_t)(b * Hh + h) * Ss + sx) * Kk + ch;
                    #pragma unroll
                    for (int r = 0; r < 4; ++r)
                        dst[(size_t)r * Kk] = (__bf16)((acc[mi][nj][r] + bia) * sc2);
                } else {
                    bf16x4 o;
                    #pragma unroll
                    for (int r = 0; r < 4; ++r) o[r] = (__bf16)(acc[mi][nj][r] + bia);
                    *(bf16x4*)(vb + ((size_t)(b * Hh + h) * Kk + ch) * Ss + sx) = o;
                }
            }
        }
    } else {
        #pragma unroll
        for (int mi = 0; mi < 8; ++mi) {
            int row = m0 + wm * 128 + mi * 16 + quad * 4;
            #pragma unroll
            for (int nj = 0; nj < 4; ++nj) {
                int n = n0 + wn * 64 + nj * 16 + l16;
                float bia = bo[n];
                #pragma unroll
                for (int r = 0; r < 4; ++r)
                    outf[(size_t)(row + r) * 1024 + n] = acc[mi][nj][r] + bia;
            }
        }
    }
}

// ---------------------------------------------------------------------------
// Flash attention: fixed-base softmax (scores bounded => no max tracking),
// wave-private P (no barrier), 32 q/wave, VGPR prefetch of next K/V tile,
// ping-pong K/V LDS (one barrier per tile), exp2 softmax, setprio on MFMA.
// Mask: p = mq ? (mk ? exp(s) : 0) : 1 — exactly matches reference semantics.
// ---------------------------------------------------------------------------
__global__ __launch_bounds__(256) void attn(
    const __bf16* __restrict__ qb, const __bf16* __restrict__ kb,
    const __bf16* __restrict__ vb, const int* __restrict__ mask,
    __bf16* __restrict__ ctx)
{
    const int bh = blockIdx.x;
    const int q0 = blockIdx.y * 128;
    const int b  = bh >> 4;
    const int h  = bh & 15;
    const size_t base = (size_t)bh * Ss * Kk;

    __shared__ __align__(16) __bf16 Qs[128][72];
    __shared__ __align__(16) __bf16 Ks[2][64][72];
    __shared__ __align__(16) __bf16 VTs[2][64][72];
    __shared__ __align__(16) __bf16 Ps[4][32][72];
    __shared__ float mkf[1024];

    const int t    = threadIdx.x;
    const int wave = t >> 6, lane = t & 63;
    const int quad = lane >> 4, l16 = lane & 15;
    const int qbase = wave * 32;

    #pragma unroll
    for (int p = 0; p < 4; ++p) {
        int idx = t + p * 256;
        int r = idx >> 3, g = idx & 7;
        *(bf16x8*)&Qs[r][g * 8] =
            *(const bf16x8*)(qb + base + (size_t)(q0 + r) * Kk + g * 8);
    }
    {
        int4 mi = *(const int4*)(mask + b * Ss + t * 4);
        mkf[t * 4 + 0] = (float)mi.x;
        mkf[t * 4 + 1] = (float)mi.y;
        mkf[t * 4 + 2] = (float)mi.z;
        mkf[t * 4 + 3] = (float)mi.w;
    }

    const int r0 = t >> 3, c0 = (t & 7) * 8;
    bf16x8 kr0, kr1, vr0, vr1;
    kr0 = *(const bf16x8*)(kb + base + (size_t)(r0) * Kk + c0);
    kr1 = *(const bf16x8*)(kb + base + (size_t)(r0 + 32) * Kk + c0);
    vr0 = *(const bf16x8*)(vb + base + (size_t)(r0) * Ss + c0);
    vr1 = *(const bf16x8*)(vb + base + (size_t)(r0 + 32) * Ss + c0);

    __syncthreads();   // Qs + mkf visible

    bf16x8 aq[2][2];
    #pragma unroll
    for (int rg = 0; rg < 2; ++rg) {
        aq[rg][0] = *(const bf16x8*)&Qs[qbase + rg * 16 + l16][quad * 8];
        aq[rg][1] = *(const bf16x8*)&Qs[qbase + rg * 16 + l16][32 + quad * 8];
    }
    float mqf[2][4], omqf[2][4];
    #pragma unroll
    for (int rg = 0; rg < 2; ++rg)
        #pragma unroll
        for (int i = 0; i < 4; ++i) {
            float m = mkf[q0 + qbase + rg * 16 + quad * 4 + i];
            mqf[rg][i] = m; omqf[rg][i] = 1.0f - m;
        }

    f32x4 O[2][4];
    float lsum[2][4];
    #pragma unroll
    for (int rg = 0; rg < 2; ++rg)
        #pragma unroll
        for (int nb = 0; nb < 4; ++nb) O[rg][nb] = (f32x4){0.f, 0.f, 0.f, 0.f};
    #pragma unroll
    for (int rg = 0; rg < 2; ++rg)
        #pragma unroll
        for (int i = 0; i < 4; ++i) lsum[rg][i] = 0.f;

    for (int kt = 0; kt < Ss; kt += 64) {
        const int p = (kt >> 6) & 1;
        *(bf16x8*)&Ks[p][r0][c0] = kr0;
        *(bf16x8*)&Ks[p][r0 + 32][c0] = kr1;
        *(bf16x8*)&VTs[p][r0][c0] = vr0;
        *(bf16x8*)&VTs[p][r0 + 32][c0] = vr1;
        __syncthreads();   // the ONLY barrier per tile

        int ktn = kt + 64;
        if (ktn < Ss) {    // issue next tile's loads; in flight across compute
            kr0 = *(const bf16x8*)(kb + base + (size_t)(ktn + r0) * Kk + c0);
            kr1 = *(const bf16x8*)(kb + base + (size_t)(ktn + r0 + 32) * Kk + c0);
            vr0 = *(const bf16x8*)(vb + base + (size_t)(r0) * Ss + ktn + c0);
            vr1 = *(const bf16x8*)(vb + base + (size_t)(r0 + 32) * Ss + ktn + c0);
        }

        float mkv[4];
        #pragma unroll
        for (int nb = 0; nb < 4; ++nb) mkv[nb] = mkf[kt + nb * 16 + l16];

        bf16x8 kb0[4], kb1[4];
        #pragma unroll
        for (int nb = 0; nb < 4; ++nb) {
            kb0[nb] = *(const bf16x8*)&Ks[p][nb * 16 + l16][quad * 8];
            kb1[nb] = *(const bf16x8*)&Ks[p][nb * 16 + l16][32 + quad * 8];
        }

        f32x4 s[2][4];
        __builtin_amdgcn_s_setprio(1);
        #pragma unroll
        for (int rg = 0; rg < 2; ++rg)
            #pragma unroll
            for (int nb = 0; nb < 4; ++nb) {
                f32x4 a = (f32x4){0.f, 0.f, 0.f, 0.f};
                a = MFMA16(aq[rg][0], kb0[nb], a);
                a = MFMA16(aq[rg][1], kb1[nb], a);
                s[rg][nb] = a;
            }
        __builtin_amdgcn_s_setprio(0);

        #pragma unroll
        for (int rg = 0; rg < 2; ++rg)
            #pragma unroll
            for (int i = 0; i < 4; ++i) {
                float ls = 0.f;
                #pragma unroll
                for (int nb = 0; nb < 4; ++nb) {
                    float pv = exp2_hw(s[rg][nb][i]) * mkv[nb];
                    pv = pv * mqf[rg][i] + omqf[rg][i];
                    Ps[wave][rg * 16 + quad * 4 + i][nb * 16 + l16] = (__bf16)pv;
                    ls += pv;
                }
                lsum[rg][i] += ls;
            }

        bf16x8 ap0[2], ap1[2];
        #pragma unroll
        for (int rg = 0; rg < 2; ++rg) {
            ap0[rg] = *(const bf16x8*)&Ps[wave][rg * 16 + l16][quad * 8];
            ap1[rg] = *(const bf16x8*)&Ps[wave][rg * 16 + l16][32 + quad * 8];
        }
        __builtin_amdgcn_s_setprio(1);
        #pragma unroll
        for (int nb = 0; nb < 4; ++nb) {
            bf16x8 vb0 = *(const bf16x8*)&VTs[p][nb * 16 + l16][quad * 8];
            bf16x8 vb1 = *(const bf16x8*)&VTs[p][nb * 16 + l16][32 + quad * 8];
            #pragma unroll
            for (int rg = 0; rg < 2; ++rg) {
                O[rg][nb] = MFMA16(ap0[rg], vb0, O[rg][nb]);
                O[rg][nb] = MFMA16(ap1[rg], vb1, O[rg][nb]);
            }
        }
        __builtin_amdgcn_s_setprio(0);
    }

    #pragma unroll
    for (int rg = 0; rg < 2; ++rg)
        #pragma unroll
        for (int i = 0; i < 4; ++i) {
            float l = lsum[rg][i];
            l += __shfl_xor(l, 1);
            l += __shfl_xor(l, 2);
            l += __shfl_xor(l, 4);
            l += __shfl_xor(l, 8);
            float inv = 1.0f / l;
            int srow = q0 + qbase + rg * 16 + quad * 4 + i;
            __bf16* dst = ctx + ((size_t)(b * Ss + srow) * Hh + h) * Kk;
            #pragma unroll
            for (int nb = 0; nb < 4; ++nb)
                dst[nb * 16 + l16] = (__bf16)(O[rg][nb][i] * inv);
        }
}

extern "C" void kernel_launch(void* const* d_in, const int* in_sizes, int n_in,
                              void* d_out, int out_size, void* d_ws, size_t ws_size,
                              hipStream_t stream) {
    const float* x    = (const float*)d_in[0];
    const int*   mask = (const int*)d_in[1];
    const float* Wq   = (const float*)d_in[2];
    const float* bq   = (const float*)d_in[3];
    const float* Wk   = (const float*)d_in[4];
    const float* bk   = (const float*)d_in[5];
    const float* Wv   = (const float*)d_in[6];
    const float* bv   = (const float*)d_in[7];
    const float* Wo   = (const float*)d_in[8];
    const float* bo   = (const float*)d_in[9];

    __bf16* xb   = (__bf16*)d_ws;
    __bf16* WT   = xb + XB_E;
    __bf16* WoT  = WT + WT_E;
    __bf16* qb   = WoT + WOT_E;
    __bf16* kb   = qb + QKV_E;
    __bf16* vb   = kb + QKV_E;
    __bf16* ctxb = vb + QKV_E;
    float* out = (float*)d_out;

    prep<<<dim3(16, 16, 5), 256, 0, stream>>>(x, Wq, Wk, Wv, Wo, xb, WT, WoT);
    gemm_bt<<<dim3(12, 32), 512, 0, stream>>>(xb, WT, 0, qb, kb, vb,
                                              bq, bk, bv, nullptr, nullptr);
    attn<<<dim3(128, 8), 256, 0, stream>>>(qb, kb, vb, mask, ctxb);
    gemm_bt<<<dim3(4, 32), 512, 0, stream>>>(ctxb, WoT, 1, nullptr, nullptr,
                                             nullptr, nullptr, nullptr, nullptr,
                                             out, bo);
}